// Round 10
// baseline (345.273 us; speedup 1.0000x reference)
//
#include <hip/hip_runtime.h>
#include <stdint.h>

typedef unsigned short ushort_t;
typedef unsigned int uint_t;
typedef _Float16 half_t;

typedef float  float4_t __attribute__((ext_vector_type(4)));
typedef float  float2_t __attribute__((ext_vector_type(2)));
typedef _Float16 half4_t __attribute__((ext_vector_type(4)));
typedef uint_t uint2_t  __attribute__((ext_vector_type(2)));

#define B_N 32
#define C_N 256
#define HALF_N 128
#define H_N 56
#define W_N 56
#define HW_N 3136
#define NPIX (B_N * HW_N)   // 100352
#define EPS_D 1e-5
#define W3S 40              // dwords per out-ch for 3x3 bits (36 used)
#define PWS 16              // dwords per out-ch for per-tap popcounts (9 used)

// ---------------------------------------------------------------------------
// prep: pack weight sign bits (bit=1 iff w>0; w<=0 -> -1) + per-(o,tap)
// popcounts + fp64 scales + degeneracy flags. Block 0 zeroes stats.
// ---------------------------------------------------------------------------
__global__ void prep_kernel(const float* __restrict__ w3, const float* __restrict__ w1,
                            uint_t* __restrict__ wbits3, uint_t* __restrict__ wbits1,
                            uint_t* __restrict__ popcw3,
                            double* __restrict__ scale3, double* __restrict__ scale1,
                            double* __restrict__ sums1, double* __restrict__ sums2,
                            uint_t* __restrict__ oflags) {
    __shared__ double red[128];
    __shared__ int ipw[2][9];
    __shared__ int flsh[2];
    int t = threadIdx.x;          // 128 threads = 2 waves (ci = t)
    int blk = blockIdx.x;         // 256 blocks
    int lane = t & 63;
    int wv = t >> 6;
    if (blk == 0) {
        sums1[t] = 0.0; sums1[128 + t] = 0.0;
        sums2[t] = 0.0; sums2[128 + t] = 0.0;
    }
    if (blk < 128) {
        int o = blk;
        double acc = 0.0;
        int anynp = 0;
        #pragma unroll
        for (int j = 0; j < 9; ++j) {
            float v = w3[o * 1152 + t * 9 + j];     // [o][ci=t][tap=j]
            acc += fabs((double)v);
            anynp |= (v <= 0.f) ? 1 : 0;
            unsigned long long b = __ballot(v > 0.f);
            if (lane == 0) {
                wbits3[o * W3S + j * 4 + wv * 2 + 0] = (uint_t)b;
                wbits3[o * W3S + j * 4 + wv * 2 + 1] = (uint_t)(b >> 32);
                ipw[wv][j] = __popcll(b);
            }
        }
        unsigned long long m = __ballot(anynp != 0);
        if (lane == 0) flsh[wv] = (m != 0ull) ? 1 : 0;
        red[t] = acc; __syncthreads();
        for (int s = 64; s > 0; s >>= 1) { if (t < s) red[t] += red[t + s]; __syncthreads(); }
        if (t == 0) { scale3[o] = red[0] / 1152.0; oflags[o] = (uint_t)(flsh[0] | flsh[1]); }
        if (t < 9) popcw3[o * PWS + t] = (uint_t)(ipw[0][t] + ipw[1][t]);
    } else {
        int o = blk - 128;
        float v = w1[o * 128 + t];
        unsigned long long b = __ballot(v > 0.f);
        unsigned long long m = __ballot(v <= 0.f);
        if (lane == 0) {
            wbits1[o * 8 + wv * 2 + 0] = (uint_t)b;
            wbits1[o * 8 + wv * 2 + 1] = (uint_t)(b >> 32);
            flsh[wv] = (m != 0ull) ? 1 : 0;
        }
        red[t] = fabs((double)v); __syncthreads();
        for (int s = 64; s > 0; s >>= 1) { if (t < s) red[t] += red[t + s]; __syncthreads(); }
        if (t == 0) { scale1[o] = red[0] / 128.0; oflags[128 + o] = (uint_t)(flsh[0] | flsh[1]); }
    }
}

// ---------------------------------------------------------------------------
// sign1: 2 px/thread, float2 x loads, uint2 vb store (r5 form — never the
// slow kernel in any profile). Same fp64 compare -> bit-identical vb1.
// Block (0,0) combines oflags into fin[2].
// ---------------------------------------------------------------------------
__global__ __launch_bounds__(256) void sign1_kernel(const float* __restrict__ x,
                                                    const float* __restrict__ b1,
                                                    uint_t* __restrict__ vb,
                                                    const uint_t* __restrict__ oflags,
                                                    uint_t* __restrict__ fin) {
    __shared__ int fl[4];
    int t = threadIdx.x;
    if (blockIdx.x == 0 && blockIdx.y == 0) {
        int lane = t & 63, wv4 = t >> 6;
        uint_t f = oflags[t];                      // t in [0,256)
        unsigned long long m = __ballot(f != 0u);
        if (lane == 0) fl[wv4] = (m != 0ull) ? 1 : 0;
        __syncthreads();
        if (t == 0) { fin[0] = (uint_t)(fl[0] | fl[1]); fin[1] = (uint_t)(fl[2] | fl[3]); }
    }
    int p = blockIdx.x * 512 + t * 2;    // 2 consecutive pixels, 8B aligned
    int cb = blockIdx.y * 32;            // 32 channels -> 1 word
    int b = p / HW_N;
    int hw = p - b * HW_N;               // HW_N even: no image crossing
    const float* xb = x + (size_t)b * C_N * HW_N + hw;
    uint_t w0 = 0, w1 = 0;
    #pragma unroll
    for (int j = 0; j < 32; ++j) {
        int c = cb + j;
        int src = ((c & 1) << 7) + (c >> 1);
        float2_t xv = *(const float2_t*)(xb + (size_t)src * HW_N);
        double bc = (double)b1[c];
        if ((double)xv[0] + bc > 0.0) w0 |= (1u << j);
        if ((double)xv[1] + bc > 0.0) w1 |= (1u << j);
    }
    uint2_t o2; o2[0] = w0; o2[1] = w1;
    *(uint2_t*)(vb + (size_t)(cb >> 5) * NPIX + p) = o2;
}

// ---------------------------------------------------------------------------
// conv3 + fused stats. FAST PATH (all w3 > 0): dot = 2*P - 128*nvalid,
// o-independent within a group. General path: popcount loop. Unchanged.
// ---------------------------------------------------------------------------
__global__ __launch_bounds__(256) void conv3_kernel(const uint_t* __restrict__ vb,
                                                    const uint_t* __restrict__ wbits3,
                                                    const uint_t* __restrict__ popcw3,
                                                    half_t* __restrict__ yh,
                                                    double* __restrict__ sums,
                                                    const uint_t* __restrict__ fin) {
    __shared__ short dlds[32][258];
    __shared__ int partS[8][32];
    __shared__ int partS2[8][32];
    int t = threadIdx.x;
    int lane = t & 63;
    int wv = t >> 6;
    bool fast = (fin[0] == 0u);
    int yb = blockIdx.y;
    if (fast && (yb & 1)) return;        // fast: only y==0 (g0) and y==2 (g1)
    int g = yb >> 1;
    int oh = yb & 1;
    int o0 = g * 64 + oh * 32;           // fast: oh==0 -> o0 = g*64
    int p = blockIdx.x * 256 + t;
    int hw = p % HW_N;
    int h = hw / W_N;
    int w = hw - h * W_N;
    const uint_t* vbase = vb + (size_t)g * 4 * NPIX;

    uint_t v[9][4];
    int inv[9];
    int nvalid = 0;
    #pragma unroll
    for (int j = 0; j < 9; ++j) {
        int kh = j / 3 - 1, kw = j - (j / 3) * 3 - 1;
        int hh = h + kh, ww = w + kw;
        bool valid = (hh >= 0) && (hh < H_N) && (ww >= 0) && (ww < W_N);
        inv[j] = valid ? 0 : 1;
        nvalid += valid ? 1 : 0;
        int off = p + kh * W_N + kw;
        #pragma unroll
        for (int q = 0; q < 4; ++q)
            v[j][q] = valid ? vbase[(size_t)q * NPIX + off] : 0u;
    }
    int base = 128 * nvalid;

    if (fast) {
        int P = 0;
        #pragma unroll
        for (int j = 0; j < 9; ++j)
            #pragma unroll
            for (int q = 0; q < 4; ++q)
                P += __popc(v[j][q]);
        int dot = 2 * P - base;
        yh[(size_t)o0 * NPIX + p] = (half_t)(float)dot;
        int s = dot, s2 = dot * dot;
        #pragma unroll
        for (int off = 32; off > 0; off >>= 1) {
            s  += __shfl_xor(s, off);
            s2 += __shfl_xor(s2, off);
        }
        if (lane == 0) { partS[0][wv] = s; partS2[0][wv] = s2; }
        __syncthreads();
        if (t == 0) {
            partS[1][0]  = partS[0][0] + partS[0][1] + partS[0][2] + partS[0][3];
            partS2[1][0] = partS2[0][0] + partS2[0][1] + partS2[0][2] + partS2[0][3];
        }
        __syncthreads();
        if (t < 64) {
            atomicAdd(&sums[o0 + t], (double)partS[1][0]);
            atomicAdd(&sums[128 + o0 + t], (double)partS2[1][0]);
        }
        return;
    }

    half_t* yrow = yh + (size_t)o0 * NPIX + p;
    for (int oi = 0; oi < 32; ++oi) {
        const uint_t* wo = wbits3 + (size_t)(o0 + oi) * W3S;
        const uint_t* pw = popcw3 + (size_t)(o0 + oi) * PWS;
        int acc = 0;
        #pragma unroll
        for (int j = 0; j < 9; ++j)
            #pragma unroll
            for (int q = 0; q < 4; ++q)
                acc += __popc(v[j][q] ^ wo[j * 4 + q]);
        int corr = 0;
        #pragma unroll
        for (int j = 0; j < 9; ++j) corr += inv[j] * (int)pw[j];
        int dot = base - 2 * (acc - corr);
        yrow[(size_t)oi * NPIX] = (half_t)(float)dot;
        dlds[oi][t] = (short)dot;
    }
    __syncthreads();
    {
        int o = t & 31, seg = t >> 5;                 // 8 segments x 32 px
        const int* r32 = (const int*)(&dlds[o][seg * 32]);
        int S = 0, S2 = 0;
        #pragma unroll
        for (int j = 0; j < 16; ++j) {
            int pr = r32[j];
            int d0 = (int)(short)(pr & 0xffff);
            int d1 = pr >> 16;
            S += d0 + d1; S2 += d0 * d0 + d1 * d1;
        }
        partS[seg][o] = S; partS2[seg][o] = S2;
    }
    __syncthreads();
    if (t < 32) {
        int S = 0, S2 = 0;
        #pragma unroll
        for (int s8 = 0; s8 < 8; ++s8) { S += partS[s8][t]; S2 += partS2[s8][t]; }
        int c = o0 + t;
        atomicAdd(&sums[c], (double)S);
        atomicAdd(&sums[128 + c], (double)S2);
    }
}

// ---------------------------------------------------------------------------
// coef entry (fp64): identical expression everywhere.
// ---------------------------------------------------------------------------
__device__ __forceinline__ void coef_entry(const double* __restrict__ sums,
                                           const double* __restrict__ scale,
                                           const float* __restrict__ gamma,
                                           const float* __restrict__ beta,
                                           int c, double* coefL) {
    double M = (double)NPIX;
    double mean = sums[c] / M;
    double var = sums[128 + c] / M - mean * mean;
    double s = scale[c];
    double r = 1.0 / sqrt(s * s * var + EPS_D);
    double g = (double)gamma[c];
    coefL[c] = s * r * g;
    coefL[128 + c] = (double)beta[c] - s * mean * r * g;
}

// fp32-coef variant for the value-only out kernel (fp64 internals, cast once).
__device__ __forceinline__ void coef_entry_f(const double* __restrict__ sums,
                                             const double* __restrict__ scale,
                                             const float* __restrict__ gamma,
                                             const float* __restrict__ beta,
                                             int c, float* cf) {
    double M = (double)NPIX;
    double mean = sums[c] / M;
    double var = sums[128 + c] / M - mean * mean;
    double s = scale[c];
    double r = 1.0 / sqrt(s * s * var + EPS_D);
    double g = (double)gamma[c];
    cf[c] = (float)(s * r * g);
    cf[128 + c] = (float)((double)beta[c] - s * mean * r * g);
}

// ---------------------------------------------------------------------------
// x2 value chain (fp64) - UNCHANGED sign-determining expression.
// ---------------------------------------------------------------------------
__device__ __forceinline__ double x2_val(double xs, double K, bool hasy,
                                         const double* coef1, int c,
                                         const float* __restrict__ b2_1, const float* __restrict__ a2,
                                         const float* __restrict__ b2_2, const float* __restrict__ b3_1) {
    int ci = c & 127;
    double t = hasy ? (coef1[ci] * K + coef1[128 + ci] + xs) : xs;
    t += (double)b2_1[c];
    double a = (double)a2[c];
    t = (t >= 0.0) ? t : a * t;
    t += (double)b2_2[c];
    t += (double)b3_1[c];
    return t;
}

// ---------------------------------------------------------------------------
// x2c1: ANCHOR FORM (1 px/thread, 128-ch unrolled chain) + ONE change:
// g=1 additionally FINALIZES output channels [128,256) (no BN3 dependence):
// out = prelu_a4(t2 + b4_1) + b4_2 (fp32 tail from the fp64 t2 already in
// hand). Saves out_kernel's 51.4MB c>=128 x-re-read. Ran correctly r4-r7.
// ---------------------------------------------------------------------------
__global__ __launch_bounds__(256) void x2c1_kernel(
        const float* __restrict__ x, const half_t* __restrict__ y1h,
        const double* __restrict__ sums1, const double* __restrict__ scale3,
        const float* __restrict__ g1, const float* __restrict__ be1,
        const float* __restrict__ b2_1, const float* __restrict__ a2,
        const float* __restrict__ b2_2, const float* __restrict__ b3_1,
        const uint_t* __restrict__ wbits1,
        half_t* __restrict__ y3h, double* __restrict__ sums2,
        const float* __restrict__ b4_1, const float* __restrict__ a4,
        const float* __restrict__ b4_2, float* __restrict__ out,
        const uint_t* __restrict__ fin) {
    __shared__ double coefL[256];
    __shared__ short dst[32][258];
    __shared__ int partS[8][32];
    __shared__ int partS2[8][32];
    int t = threadIdx.x;
    int lane = t & 63;
    int wv = t >> 6;
    int g = blockIdx.y;
    bool fast3 = (fin[0] == 0u);
    bool fast1 = (fin[1] == 0u);
    if (g == 0 && t < 128) coef_entry(sums1, scale3, g1, be1, t, coefL);
    __syncthreads();

    int p = blockIdx.x * 256 + t;
    int b = p / HW_N;
    int hw = p - b * HW_N;
    const float* xb = x + (size_t)b * C_N * HW_N + hw;
    int c0 = g * 128;

    uint_t w0_, w1_, w2_, w3_;
    if (g == 0) {
        if (fast3) {
            double K0  = (double)(float)y1h[p];
            double K64 = (double)(float)y1h[(size_t)64 * NPIX + p];
            #pragma unroll
            for (int wq = 0; wq < 4; ++wq) {
                uint_t bits = 0u;
                double Kc = (wq < 2) ? K0 : K64;
                #pragma unroll
                for (int j = 0; j < 32; ++j) {
                    int c = wq * 32 + j;
                    int src = ((c & 1) << 7) + (c >> 1);
                    double xs = (double)xb[(size_t)src * HW_N];
                    double v = x2_val(xs, Kc, true, coefL, c, b2_1, a2, b2_2, b3_1);
                    bits |= (v > 0.0) ? (1u << j) : 0u;
                }
                if (wq == 0) w0_ = bits; else if (wq == 1) w1_ = bits;
                else if (wq == 2) w2_ = bits; else w3_ = bits;
            }
        } else {
            #pragma unroll
            for (int wq = 0; wq < 4; ++wq) {
                uint_t bits = 0u;
                #pragma unroll
                for (int j = 0; j < 32; ++j) {
                    int c = wq * 32 + j;
                    int src = ((c & 1) << 7) + (c >> 1);
                    double xs = (double)xb[(size_t)src * HW_N];
                    double K = (double)(float)y1h[(size_t)c * NPIX + p];
                    double v = x2_val(xs, K, true, coefL, c, b2_1, a2, b2_2, b3_1);
                    bits |= (v > 0.0) ? (1u << j) : 0u;
                }
                if (wq == 0) w0_ = bits; else if (wq == 1) w1_ = bits;
                else if (wq == 2) w2_ = bits; else w3_ = bits;
            }
        }
    } else {
        #pragma unroll
        for (int wq = 0; wq < 4; ++wq) {
            uint_t bits = 0u;
            #pragma unroll
            for (int j = 0; j < 32; ++j) {
                int c = c0 + wq * 32 + j;            // global c in [128,256)
                int src = ((c & 1) << 7) + (c >> 1);
                double xs = (double)xb[(size_t)src * HW_N];
                double v = x2_val(xs, 0.0, false, coefL, c, b2_1, a2, b2_2, b3_1);
                bits |= (v > 0.0) ? (1u << j) : 0u;
                // finalize output channel c (no BN3 dependence), fp32 tail
                float f0 = (float)v + b4_1[c];
                f0 = (f0 >= 0.f) ? f0 : a4[c] * f0;
                f0 += b4_2[c];
                out[((size_t)b * C_N + c) * HW_N + hw] = f0;
            }
            if (wq == 0) w0_ = bits; else if (wq == 1) w1_ = bits;
            else if (wq == 2) w2_ = bits; else w3_ = bits;
        }
    }

    int obase = g * 64;
    if (fast1) {
        int P = __popc(w0_) + __popc(w1_) + __popc(w2_) + __popc(w3_);
        int dotv = 2 * P - 128;
        y3h[(size_t)obase * NPIX + p] = (half_t)(float)dotv;
        int s = dotv, s2 = dotv * dotv;
        #pragma unroll
        for (int off = 32; off > 0; off >>= 1) {
            s  += __shfl_xor(s, off);
            s2 += __shfl_xor(s2, off);
        }
        if (lane == 0) { partS[0][wv] = s; partS2[0][wv] = s2; }
        __syncthreads();
        if (t == 0) {
            partS[1][0]  = partS[0][0] + partS[0][1] + partS[0][2] + partS[0][3];
            partS2[1][0] = partS2[0][0] + partS2[0][1] + partS2[0][2] + partS2[0][3];
        }
        __syncthreads();
        if (t < 64) {
            atomicAdd(&sums2[obase + t], (double)partS[1][0]);
            atomicAdd(&sums2[128 + obase + t], (double)partS2[1][0]);
        }
        return;
    }

    #pragma unroll
    for (int ch = 0; ch < 2; ++ch) {
        #pragma unroll
        for (int oi = 0; oi < 32; ++oi) {
            int o = obase + ch * 32 + oi;
            const uint_t* wo = wbits1 + (size_t)o * 8;   // wave-uniform -> s_load
            int acc = __popc(w0_ ^ wo[0]) + __popc(w1_ ^ wo[1])
                    + __popc(w2_ ^ wo[2]) + __popc(w3_ ^ wo[3]);
            int dot = 128 - 2 * acc;
            y3h[(size_t)o * NPIX + p] = (half_t)(float)dot;
            dst[oi][t] = (short)dot;
        }
        __syncthreads();
        {
            int o = t & 31, seg = t >> 5;               // 8 segments x 32 px
            const int* r32 = (const int*)(&dst[o][seg * 32]);
            int S = 0, S2 = 0;
            #pragma unroll
            for (int j = 0; j < 16; ++j) {
                int pr = r32[j];
                int d0 = (int)(short)(pr & 0xffff);
                int d1 = pr >> 16;
                S += d0 + d1; S2 += d0 * d0 + d1 * d1;
            }
            partS[seg][o] = S; partS2[seg][o] = S2;
        }
        __syncthreads();
        if (t < 32) {
            int S = 0, S2 = 0;
            #pragma unroll
            for (int s8 = 0; s8 < 8; ++s8) { S += partS[s8][t]; S2 += partS2[s8][t]; }
            int c = obase + ch * 32 + t;
            atomicAdd(&sums2[c], (double)S);
            atomicAdd(&sums2[128 + c], (double)S2);
        }
        __syncthreads();   // protect dst before next chunk's writes
    }
}

// ---------------------------------------------------------------------------
// out: only c < 128 now (c >= 128 finalized in x2c1). fp32 value chain,
// float4 x/out, half4 y loads.
// ---------------------------------------------------------------------------
__global__ __launch_bounds__(256) void out_kernel(
        const float* __restrict__ x, const half_t* __restrict__ y1h,
        const half_t* __restrict__ y3h,
        const double* __restrict__ sums1, const double* __restrict__ scale3,
        const float* __restrict__ g1, const float* __restrict__ be1,
        const double* __restrict__ sums2, const double* __restrict__ scale1,
        const float* __restrict__ g3, const float* __restrict__ be3,
        const float* __restrict__ b2_1, const float* __restrict__ a2,
        const float* __restrict__ b2_2, const float* __restrict__ b3_1,
        const float* __restrict__ b4_1, const float* __restrict__ a4,
        const float* __restrict__ b4_2, float* __restrict__ out,
        const uint_t* __restrict__ fin) {
    __shared__ float c1f[256];
    __shared__ float c3f[256];
    int t = threadIdx.x;
    if (t < 128) coef_entry_f(sums1, scale3, g1, be1, t, c1f);
    else coef_entry_f(sums2, scale1, g3, be3, t - 128, c3f);
    __syncthreads();
    int c = blockIdx.y;                  // < 128
    int src = ((c & 1) << 7) + (c >> 1);
    int y1slice = (fin[0] == 0u) ? ((c < 64) ? 0 : 64) : c;
    int y3slice = (fin[1] == 0u) ? ((c < 64) ? 0 : 64) : c;
    float b21 = b2_1[c], aa2v = a2[c], b23 = b2_2[c] + b3_1[c];
    float b41 = b4_1[c], aa4v = a4[c], b42 = b4_2[c];
    float c1 = c1f[c], c1b = c1f[128 + c];
    float c3 = c3f[c], c3b = c3f[128 + c];
    const half_t* y1p = y1h + (size_t)y1slice * NPIX;
    const half_t* y3p = y3h + (size_t)y3slice * NPIX;
    #pragma unroll
    for (int i = 0; i < 2; ++i) {
        int p = blockIdx.x * 2048 + i * 1024 + t * 4;
        int b = p / HW_N;
        int hw = p - b * HW_N;           // HW_N % 4 == 0: no image crossing
        float4_t xs = *(const float4_t*)(x + ((size_t)b * C_N + src) * HW_N + hw);
        half4_t y1v = *(const half4_t*)(y1p + p);
        half4_t y3v = *(const half4_t*)(y3p + p);
        float4_t ov;
        #pragma unroll
        for (int k = 0; k < 4; ++k) {
            float v = fmaf(c1, (float)y1v[k], c1b) + xs[k];
            v += b21;
            v = (v >= 0.f) ? v : aa2v * v;
            v += b23;
            float t2 = v;
            v = fmaf(c3, (float)y3v[k], c3b) + t2;
            v += b41;
            v = (v >= 0.f) ? v : aa4v * v;
            v += b42;
            ov[k] = v;
        }
        *(float4_t*)(out + ((size_t)b * C_N + c) * HW_N + hw) = ov;
    }
}

extern "C" void kernel_launch(void* const* d_in, const int* in_sizes, int n_in,
                              void* d_out, int out_size, void* d_ws, size_t ws_size,
                              hipStream_t stream) {
    const float* x    = (const float*)d_in[0];
    const float* w3   = (const float*)d_in[1];
    const float* w1   = (const float*)d_in[2];
    const float* b1   = (const float*)d_in[3];
    const float* g1   = (const float*)d_in[4];
    const float* be1  = (const float*)d_in[5];
    const float* b2_1 = (const float*)d_in[6];
    const float* a2   = (const float*)d_in[7];
    const float* b2_2 = (const float*)d_in[8];
    const float* b3_1 = (const float*)d_in[9];
    const float* g3   = (const float*)d_in[10];
    const float* be3  = (const float*)d_in[11];
    const float* b4_1 = (const float*)d_in[12];
    const float* a4   = (const float*)d_in[13];
    const float* b4_2 = (const float*)d_in[14];

    // workspace (~51.5 MB)
    char* ws = (char*)d_ws;
    half_t* y1h    = (half_t*)(ws + 0);                 // 25,690,112
    half_t* y3h    = (half_t*)(ws + 25690112);          // 25,690,112
    uint_t* wbits3 = (uint_t*)(ws + 51380224);          // 20,480
    uint_t* wbits1 = (uint_t*)(ws + 51400704);          // 4,096
    uint_t* popcw3 = (uint_t*)(ws + 51404800);          // 8,192
    double* scale3 = (double*)(ws + 51412992);          // 1,024
    double* scale1 = (double*)(ws + 51414016);          // 1,024
    double* sums1  = (double*)(ws + 51415040);          // 2,048
    double* sums2  = (double*)(ws + 51417088);          // 2,048
    uint_t* oflags = (uint_t*)(ws + 51419136);          // 1,024
    uint_t* fin    = (uint_t*)(ws + 51420160);          // 8

    // packed sign planes for conv3 live in d_out (consumed before x2c1/out
    // overwrite d_out; vb1 is dead after conv3 - stream order guarantees it).
    uint_t* vb1 = (uint_t*)((char*)d_out + 0);          // 8*NPIX*4 = 3,211,264
    float*  outp = (float*)d_out;

    prep_kernel<<<256, 128, 0, stream>>>(w3, w1, wbits3, wbits1, popcw3,
                                         scale3, scale1, sums1, sums2, oflags);
    sign1_kernel<<<dim3(NPIX / 512, 8), 256, 0, stream>>>(x, b1, vb1, oflags, fin);
    conv3_kernel<<<dim3(NPIX / 256, 4), 256, 0, stream>>>(vb1, wbits3, popcw3, y1h, sums1, fin);
    x2c1_kernel<<<dim3(NPIX / 256, 2), 256, 0, stream>>>(x, y1h, sums1, scale3, g1, be1,
                                                         b2_1, a2, b2_2, b3_1,
                                                         wbits1, y3h, sums2,
                                                         b4_1, a4, b4_2, outp, fin);
    out_kernel<<<dim3(NPIX / 2048, 128), 256, 0, stream>>>(x, y1h, y3h,
                                                           sums1, scale3, g1, be1,
                                                           sums2, scale1, g3, be3,
                                                           b2_1, a2, b2_2, b3_1,
                                                           b4_1, a4, b4_2, outp, fin);
}

// Round 11
// 270.554 us; speedup vs baseline: 1.2762x; 1.2762x over previous
//
#include <hip/hip_runtime.h>
#include <stdint.h>

typedef unsigned short ushort_t;
typedef unsigned int uint_t;
typedef _Float16 half_t;

typedef float  float4_t __attribute__((ext_vector_type(4)));
typedef float  float2_t __attribute__((ext_vector_type(2)));
typedef _Float16 half4_t __attribute__((ext_vector_type(4)));
typedef uint_t uint2_t  __attribute__((ext_vector_type(2)));

#define B_N 32
#define C_N 256
#define HALF_N 128
#define H_N 56
#define W_N 56
#define HW_N 3136
#define NPIX (B_N * HW_N)   // 100352
#define EPS_D 1e-5
#define W3S 40              // dwords per out-ch for 3x3 bits (36 used)
#define PWS 16              // dwords per out-ch for per-tap popcounts (9 used)

// ---------------------------------------------------------------------------
// prep: pack weight sign bits (bit=1 iff w>0; w<=0 -> -1) + per-(o,tap)
// popcounts + fp64 scales + degeneracy flags. Block 0 zeroes stats.
// ---------------------------------------------------------------------------
__global__ void prep_kernel(const float* __restrict__ w3, const float* __restrict__ w1,
                            uint_t* __restrict__ wbits3, uint_t* __restrict__ wbits1,
                            uint_t* __restrict__ popcw3,
                            double* __restrict__ scale3, double* __restrict__ scale1,
                            double* __restrict__ sums1, double* __restrict__ sums2,
                            uint_t* __restrict__ oflags) {
    __shared__ double red[128];
    __shared__ int ipw[2][9];
    __shared__ int flsh[2];
    int t = threadIdx.x;          // 128 threads = 2 waves (ci = t)
    int blk = blockIdx.x;         // 256 blocks
    int lane = t & 63;
    int wv = t >> 6;
    if (blk == 0) {
        sums1[t] = 0.0; sums1[128 + t] = 0.0;
        sums2[t] = 0.0; sums2[128 + t] = 0.0;
    }
    if (blk < 128) {
        int o = blk;
        double acc = 0.0;
        int anynp = 0;
        #pragma unroll
        for (int j = 0; j < 9; ++j) {
            float v = w3[o * 1152 + t * 9 + j];     // [o][ci=t][tap=j]
            acc += fabs((double)v);
            anynp |= (v <= 0.f) ? 1 : 0;
            unsigned long long b = __ballot(v > 0.f);
            if (lane == 0) {
                wbits3[o * W3S + j * 4 + wv * 2 + 0] = (uint_t)b;
                wbits3[o * W3S + j * 4 + wv * 2 + 1] = (uint_t)(b >> 32);
                ipw[wv][j] = __popcll(b);
            }
        }
        unsigned long long m = __ballot(anynp != 0);
        if (lane == 0) flsh[wv] = (m != 0ull) ? 1 : 0;
        red[t] = acc; __syncthreads();
        for (int s = 64; s > 0; s >>= 1) { if (t < s) red[t] += red[t + s]; __syncthreads(); }
        if (t == 0) { scale3[o] = red[0] / 1152.0; oflags[o] = (uint_t)(flsh[0] | flsh[1]); }
        if (t < 9) popcw3[o * PWS + t] = (uint_t)(ipw[0][t] + ipw[1][t]);
    } else {
        int o = blk - 128;
        float v = w1[o * 128 + t];
        unsigned long long b = __ballot(v > 0.f);
        unsigned long long m = __ballot(v <= 0.f);
        if (lane == 0) {
            wbits1[o * 8 + wv * 2 + 0] = (uint_t)b;
            wbits1[o * 8 + wv * 2 + 1] = (uint_t)(b >> 32);
            flsh[wv] = (m != 0ull) ? 1 : 0;
        }
        red[t] = fabs((double)v); __syncthreads();
        for (int s = 64; s > 0; s >>= 1) { if (t < s) red[t] += red[t + s]; __syncthreads(); }
        if (t == 0) { scale1[o] = red[0] / 128.0; oflags[128 + o] = (uint_t)(flsh[0] | flsh[1]); }
    }
}

// ---------------------------------------------------------------------------
// sign1: 2 px/thread, float2 x loads, uint2 vb store. Same fp64 compare ->
// bit-identical vb1. Block (0,0) combines oflags into fin[2].
// ---------------------------------------------------------------------------
__global__ __launch_bounds__(256) void sign1_kernel(const float* __restrict__ x,
                                                    const float* __restrict__ b1,
                                                    uint_t* __restrict__ vb,
                                                    const uint_t* __restrict__ oflags,
                                                    uint_t* __restrict__ fin) {
    __shared__ int fl[4];
    int t = threadIdx.x;
    if (blockIdx.x == 0 && blockIdx.y == 0) {
        int lane = t & 63, wv4 = t >> 6;
        uint_t f = oflags[t];                      // t in [0,256)
        unsigned long long m = __ballot(f != 0u);
        if (lane == 0) fl[wv4] = (m != 0ull) ? 1 : 0;
        __syncthreads();
        if (t == 0) { fin[0] = (uint_t)(fl[0] | fl[1]); fin[1] = (uint_t)(fl[2] | fl[3]); }
    }
    int p = blockIdx.x * 512 + t * 2;    // 2 consecutive pixels, 8B aligned
    int cb = blockIdx.y * 32;            // 32 channels -> 1 word
    int b = p / HW_N;
    int hw = p - b * HW_N;               // HW_N even: no image crossing
    const float* xb = x + (size_t)b * C_N * HW_N + hw;
    uint_t w0 = 0, w1 = 0;
    #pragma unroll
    for (int j = 0; j < 32; ++j) {
        int c = cb + j;
        int src = ((c & 1) << 7) + (c >> 1);
        float2_t xv = *(const float2_t*)(xb + (size_t)src * HW_N);
        double bc = (double)b1[c];
        if ((double)xv[0] + bc > 0.0) w0 |= (1u << j);
        if ((double)xv[1] + bc > 0.0) w1 |= (1u << j);
    }
    uint2_t o2; o2[0] = w0; o2[1] = w1;
    *(uint2_t*)(vb + (size_t)(cb >> 5) * NPIX + p) = o2;
}

// ---------------------------------------------------------------------------
// conv3 + fused stats. FAST PATH (all w3 > 0): dot = 2*P - 128*nvalid,
// o-independent within a group. General path: popcount loop.
// ---------------------------------------------------------------------------
__global__ __launch_bounds__(256) void conv3_kernel(const uint_t* __restrict__ vb,
                                                    const uint_t* __restrict__ wbits3,
                                                    const uint_t* __restrict__ popcw3,
                                                    half_t* __restrict__ yh,
                                                    double* __restrict__ sums,
                                                    const uint_t* __restrict__ fin) {
    __shared__ short dlds[32][258];
    __shared__ int partS[8][32];
    __shared__ int partS2[8][32];
    int t = threadIdx.x;
    int lane = t & 63;
    int wv = t >> 6;
    bool fast = (fin[0] == 0u);
    int yb = blockIdx.y;
    if (fast && (yb & 1)) return;        // fast: only y==0 (g0) and y==2 (g1)
    int g = yb >> 1;
    int oh = yb & 1;
    int o0 = g * 64 + oh * 32;           // fast: oh==0 -> o0 = g*64
    int p = blockIdx.x * 256 + t;
    int hw = p % HW_N;
    int h = hw / W_N;
    int w = hw - h * W_N;
    const uint_t* vbase = vb + (size_t)g * 4 * NPIX;

    uint_t v[9][4];
    int inv[9];
    int nvalid = 0;
    #pragma unroll
    for (int j = 0; j < 9; ++j) {
        int kh = j / 3 - 1, kw = j - (j / 3) * 3 - 1;
        int hh = h + kh, ww = w + kw;
        bool valid = (hh >= 0) && (hh < H_N) && (ww >= 0) && (ww < W_N);
        inv[j] = valid ? 0 : 1;
        nvalid += valid ? 1 : 0;
        int off = p + kh * W_N + kw;
        #pragma unroll
        for (int q = 0; q < 4; ++q)
            v[j][q] = valid ? vbase[(size_t)q * NPIX + off] : 0u;
    }
    int base = 128 * nvalid;

    if (fast) {
        int P = 0;
        #pragma unroll
        for (int j = 0; j < 9; ++j)
            #pragma unroll
            for (int q = 0; q < 4; ++q)
                P += __popc(v[j][q]);
        int dot = 2 * P - base;
        yh[(size_t)o0 * NPIX + p] = (half_t)(float)dot;
        int s = dot, s2 = dot * dot;
        #pragma unroll
        for (int off = 32; off > 0; off >>= 1) {
            s  += __shfl_xor(s, off);
            s2 += __shfl_xor(s2, off);
        }
        if (lane == 0) { partS[0][wv] = s; partS2[0][wv] = s2; }
        __syncthreads();
        if (t == 0) {
            partS[1][0]  = partS[0][0] + partS[0][1] + partS[0][2] + partS[0][3];
            partS2[1][0] = partS2[0][0] + partS2[0][1] + partS2[0][2] + partS2[0][3];
        }
        __syncthreads();
        if (t < 64) {
            atomicAdd(&sums[o0 + t], (double)partS[1][0]);
            atomicAdd(&sums[128 + o0 + t], (double)partS2[1][0]);
        }
        return;
    }

    half_t* yrow = yh + (size_t)o0 * NPIX + p;
    for (int oi = 0; oi < 32; ++oi) {
        const uint_t* wo = wbits3 + (size_t)(o0 + oi) * W3S;
        const uint_t* pw = popcw3 + (size_t)(o0 + oi) * PWS;
        int acc = 0;
        #pragma unroll
        for (int j = 0; j < 9; ++j)
            #pragma unroll
            for (int q = 0; q < 4; ++q)
                acc += __popc(v[j][q] ^ wo[j * 4 + q]);
        int corr = 0;
        #pragma unroll
        for (int j = 0; j < 9; ++j) corr += inv[j] * (int)pw[j];
        int dot = base - 2 * (acc - corr);
        yrow[(size_t)oi * NPIX] = (half_t)(float)dot;
        dlds[oi][t] = (short)dot;
    }
    __syncthreads();
    {
        int o = t & 31, seg = t >> 5;                 // 8 segments x 32 px
        const int* r32 = (const int*)(&dlds[o][seg * 32]);
        int S = 0, S2 = 0;
        #pragma unroll
        for (int j = 0; j < 16; ++j) {
            int pr = r32[j];
            int d0 = (int)(short)(pr & 0xffff);
            int d1 = pr >> 16;
            S += d0 + d1; S2 += d0 * d0 + d1 * d1;
        }
        partS[seg][o] = S; partS2[seg][o] = S2;
    }
    __syncthreads();
    if (t < 32) {
        int S = 0, S2 = 0;
        #pragma unroll
        for (int s8 = 0; s8 < 8; ++s8) { S += partS[s8][t]; S2 += partS2[s8][t]; }
        int c = o0 + t;
        atomicAdd(&sums[c], (double)S);
        atomicAdd(&sums[128 + c], (double)S2);
    }
}

// ---------------------------------------------------------------------------
// coef entry (fp64): identical expression everywhere.
// ---------------------------------------------------------------------------
__device__ __forceinline__ void coef_entry(const double* __restrict__ sums,
                                           const double* __restrict__ scale,
                                           const float* __restrict__ gamma,
                                           const float* __restrict__ beta,
                                           int c, double* coefL) {
    double M = (double)NPIX;
    double mean = sums[c] / M;
    double var = sums[128 + c] / M - mean * mean;
    double s = scale[c];
    double r = 1.0 / sqrt(s * s * var + EPS_D);
    double g = (double)gamma[c];
    coefL[c] = s * r * g;
    coefL[128 + c] = (double)beta[c] - s * mean * r * g;
}

// fp32-coef variant for the value-only out kernel (fp64 internals, cast once).
__device__ __forceinline__ void coef_entry_f(const double* __restrict__ sums,
                                             const double* __restrict__ scale,
                                             const float* __restrict__ gamma,
                                             const float* __restrict__ beta,
                                             int c, float* cf) {
    double M = (double)NPIX;
    double mean = sums[c] / M;
    double var = sums[128 + c] / M - mean * mean;
    double s = scale[c];
    double r = 1.0 / sqrt(s * s * var + EPS_D);
    double g = (double)gamma[c];
    cf[c] = (float)(s * r * g);
    cf[128 + c] = (float)((double)beta[c] - s * mean * r * g);
}

// ---------------------------------------------------------------------------
// x2 value chain (fp64) - UNCHANGED sign-determining expression.
// ---------------------------------------------------------------------------
__device__ __forceinline__ double x2_val(double xs, double K, bool hasy,
                                         const double* coef1, int c,
                                         const float* __restrict__ b2_1, const float* __restrict__ a2,
                                         const float* __restrict__ b2_2, const float* __restrict__ b3_1) {
    int ci = c & 127;
    double t = hasy ? (coef1[ci] * K + coef1[128 + ci] + xs) : xs;
    t += (double)b2_1[c];
    double a = (double)a2[c];
    t = (t >= 0.0) ? t : a * t;
    t += (double)b2_2[c];
    t += (double)b3_1[c];
    return t;
}

// ---------------------------------------------------------------------------
// x2c1: ANCHOR FORM, byte-identical to the round-9 272.9µs version.
// RULE (r5, r10 evidence): the 32x4 unrolled fp64 loop tolerates ZERO
// additions — any extra live values (e.g. out-finalize) blow VGPR 68->136
// and halve occupancy.
// ---------------------------------------------------------------------------
__global__ __launch_bounds__(256) void x2c1_kernel(
        const float* __restrict__ x, const half_t* __restrict__ y1h,
        const double* __restrict__ sums1, const double* __restrict__ scale3,
        const float* __restrict__ g1, const float* __restrict__ be1,
        const float* __restrict__ b2_1, const float* __restrict__ a2,
        const float* __restrict__ b2_2, const float* __restrict__ b3_1,
        const uint_t* __restrict__ wbits1,
        half_t* __restrict__ y3h, double* __restrict__ sums2,
        const uint_t* __restrict__ fin) {
    __shared__ double coefL[256];
    __shared__ short dst[32][258];
    __shared__ int partS[8][32];
    __shared__ int partS2[8][32];
    int t = threadIdx.x;
    int lane = t & 63;
    int wv = t >> 6;
    int g = blockIdx.y;
    bool fast3 = (fin[0] == 0u);
    bool fast1 = (fin[1] == 0u);
    if (g == 0 && t < 128) coef_entry(sums1, scale3, g1, be1, t, coefL);
    __syncthreads();

    int p = blockIdx.x * 256 + t;
    int b = p / HW_N;
    int hw = p - b * HW_N;
    const float* xb = x + (size_t)b * C_N * HW_N + hw;
    int c0 = g * 128;

    uint_t w0_, w1_, w2_, w3_;
    if (g == 0) {
        if (fast3) {
            double K0  = (double)(float)y1h[p];
            double K64 = (double)(float)y1h[(size_t)64 * NPIX + p];
            #pragma unroll
            for (int wq = 0; wq < 4; ++wq) {
                uint_t bits = 0u;
                double Kc = (wq < 2) ? K0 : K64;
                #pragma unroll
                for (int j = 0; j < 32; ++j) {
                    int c = wq * 32 + j;
                    int src = ((c & 1) << 7) + (c >> 1);
                    double xs = (double)xb[(size_t)src * HW_N];
                    double v = x2_val(xs, Kc, true, coefL, c, b2_1, a2, b2_2, b3_1);
                    bits |= (v > 0.0) ? (1u << j) : 0u;
                }
                if (wq == 0) w0_ = bits; else if (wq == 1) w1_ = bits;
                else if (wq == 2) w2_ = bits; else w3_ = bits;
            }
        } else {
            #pragma unroll
            for (int wq = 0; wq < 4; ++wq) {
                uint_t bits = 0u;
                #pragma unroll
                for (int j = 0; j < 32; ++j) {
                    int c = wq * 32 + j;
                    int src = ((c & 1) << 7) + (c >> 1);
                    double xs = (double)xb[(size_t)src * HW_N];
                    double K = (double)(float)y1h[(size_t)c * NPIX + p];
                    double v = x2_val(xs, K, true, coefL, c, b2_1, a2, b2_2, b3_1);
                    bits |= (v > 0.0) ? (1u << j) : 0u;
                }
                if (wq == 0) w0_ = bits; else if (wq == 1) w1_ = bits;
                else if (wq == 2) w2_ = bits; else w3_ = bits;
            }
        }
    } else {
        #pragma unroll
        for (int wq = 0; wq < 4; ++wq) {
            uint_t bits = 0u;
            #pragma unroll
            for (int j = 0; j < 32; ++j) {
                int c = c0 + wq * 32 + j;            // global c in [128,256)
                int src = ((c & 1) << 7) + (c >> 1);
                double xs = (double)xb[(size_t)src * HW_N];
                double v = x2_val(xs, 0.0, false, coefL, c, b2_1, a2, b2_2, b3_1);
                bits |= (v > 0.0) ? (1u << j) : 0u;
            }
            if (wq == 0) w0_ = bits; else if (wq == 1) w1_ = bits;
            else if (wq == 2) w2_ = bits; else w3_ = bits;
        }
    }

    int obase = g * 64;
    if (fast1) {
        int P = __popc(w0_) + __popc(w1_) + __popc(w2_) + __popc(w3_);
        int dotv = 2 * P - 128;
        y3h[(size_t)obase * NPIX + p] = (half_t)(float)dotv;
        int s = dotv, s2 = dotv * dotv;
        #pragma unroll
        for (int off = 32; off > 0; off >>= 1) {
            s  += __shfl_xor(s, off);
            s2 += __shfl_xor(s2, off);
        }
        if (lane == 0) { partS[0][wv] = s; partS2[0][wv] = s2; }
        __syncthreads();
        if (t == 0) {
            partS[1][0]  = partS[0][0] + partS[0][1] + partS[0][2] + partS[0][3];
            partS2[1][0] = partS2[0][0] + partS2[0][1] + partS2[0][2] + partS2[0][3];
        }
        __syncthreads();
        if (t < 64) {
            atomicAdd(&sums2[obase + t], (double)partS[1][0]);
            atomicAdd(&sums2[128 + obase + t], (double)partS2[1][0]);
        }
        return;
    }

    #pragma unroll
    for (int ch = 0; ch < 2; ++ch) {
        #pragma unroll
        for (int oi = 0; oi < 32; ++oi) {
            int o = obase + ch * 32 + oi;
            const uint_t* wo = wbits1 + (size_t)o * 8;   // wave-uniform -> s_load
            int acc = __popc(w0_ ^ wo[0]) + __popc(w1_ ^ wo[1])
                    + __popc(w2_ ^ wo[2]) + __popc(w3_ ^ wo[3]);
            int dot = 128 - 2 * acc;
            y3h[(size_t)o * NPIX + p] = (half_t)(float)dot;
            dst[oi][t] = (short)dot;
        }
        __syncthreads();
        {
            int o = t & 31, seg = t >> 5;               // 8 segments x 32 px
            const int* r32 = (const int*)(&dst[o][seg * 32]);
            int S = 0, S2 = 0;
            #pragma unroll
            for (int j = 0; j < 16; ++j) {
                int pr = r32[j];
                int d0 = (int)(short)(pr & 0xffff);
                int d1 = pr >> 16;
                S += d0 + d1; S2 += d0 * d0 + d1 * d1;
            }
            partS[seg][o] = S; partS2[seg][o] = S2;
        }
        __syncthreads();
        if (t < 32) {
            int S = 0, S2 = 0;
            #pragma unroll
            for (int s8 = 0; s8 < 8; ++s8) { S += partS[s8][t]; S2 += partS2[s8][t]; }
            int c = obase + ch * 32 + t;
            atomicAdd(&sums2[c], (double)S);
            atomicAdd(&sums2[128 + c], (double)S2);
        }
        __syncthreads();   // protect dst before next chunk's writes
    }
}

// ---------------------------------------------------------------------------
// out: full c in [0,256) (round-9 measured form). fp32 value chain,
// float4 x/out, half4 y loads.
// ---------------------------------------------------------------------------
__global__ __launch_bounds__(256) void out_kernel(
        const float* __restrict__ x, const half_t* __restrict__ y1h,
        const half_t* __restrict__ y3h,
        const double* __restrict__ sums1, const double* __restrict__ scale3,
        const float* __restrict__ g1, const float* __restrict__ be1,
        const double* __restrict__ sums2, const double* __restrict__ scale1,
        const float* __restrict__ g3, const float* __restrict__ be3,
        const float* __restrict__ b2_1, const float* __restrict__ a2,
        const float* __restrict__ b2_2, const float* __restrict__ b3_1,
        const float* __restrict__ b4_1, const float* __restrict__ a4,
        const float* __restrict__ b4_2, float* __restrict__ out,
        const uint_t* __restrict__ fin) {
    __shared__ float c1f[256];
    __shared__ float c3f[256];
    int t = threadIdx.x;
    if (t < 128) coef_entry_f(sums1, scale3, g1, be1, t, c1f);
    else coef_entry_f(sums2, scale1, g3, be3, t - 128, c3f);
    __syncthreads();
    int c = blockIdx.y;
    bool h1 = (c < 128);
    int src = ((c & 1) << 7) + (c >> 1);
    int ci = c & 127;
    int y1slice = (fin[0] == 0u) ? ((ci < 64) ? 0 : 64) : ci;
    int y3slice = (fin[1] == 0u) ? ((ci < 64) ? 0 : 64) : ci;
    float b21 = b2_1[c], aa2v = a2[c], b23 = b2_2[c] + b3_1[c];
    float b41 = b4_1[c], aa4v = a4[c], b42 = b4_2[c];
    float c1 = c1f[ci], c1b = c1f[128 + ci];
    float c3 = c3f[ci], c3b = c3f[128 + ci];
    const half_t* y1p = y1h + (size_t)y1slice * NPIX;
    const half_t* y3p = y3h + (size_t)y3slice * NPIX;
    #pragma unroll
    for (int i = 0; i < 2; ++i) {
        int p = blockIdx.x * 2048 + i * 1024 + t * 4;
        int b = p / HW_N;
        int hw = p - b * HW_N;           // HW_N % 4 == 0: no image crossing
        float4_t xs = *(const float4_t*)(x + ((size_t)b * C_N + src) * HW_N + hw);
        half4_t y1v = *(const half4_t*)(y1p + p);
        half4_t y3v = *(const half4_t*)(y3p + p);
        float4_t ov;
        #pragma unroll
        for (int k = 0; k < 4; ++k) {
            float v = h1 ? fmaf(c1, (float)y1v[k], c1b) + xs[k] : xs[k];
            v += b21;
            v = (v >= 0.f) ? v : aa2v * v;
            v += b23;
            float t2 = v;
            if (h1) v = fmaf(c3, (float)y3v[k], c3b) + t2;
            v += b41;
            v = (v >= 0.f) ? v : aa4v * v;
            v += b42;
            ov[k] = v;
        }
        *(float4_t*)(out + ((size_t)b * C_N + c) * HW_N + hw) = ov;
    }
}

extern "C" void kernel_launch(void* const* d_in, const int* in_sizes, int n_in,
                              void* d_out, int out_size, void* d_ws, size_t ws_size,
                              hipStream_t stream) {
    const float* x    = (const float*)d_in[0];
    const float* w3   = (const float*)d_in[1];
    const float* w1   = (const float*)d_in[2];
    const float* b1   = (const float*)d_in[3];
    const float* g1   = (const float*)d_in[4];
    const float* be1  = (const float*)d_in[5];
    const float* b2_1 = (const float*)d_in[6];
    const float* a2   = (const float*)d_in[7];
    const float* b2_2 = (const float*)d_in[8];
    const float* b3_1 = (const float*)d_in[9];
    const float* g3   = (const float*)d_in[10];
    const float* be3  = (const float*)d_in[11];
    const float* b4_1 = (const float*)d_in[12];
    const float* a4   = (const float*)d_in[13];
    const float* b4_2 = (const float*)d_in[14];

    // workspace (~51.5 MB)
    char* ws = (char*)d_ws;
    half_t* y1h    = (half_t*)(ws + 0);                 // 25,690,112
    half_t* y3h    = (half_t*)(ws + 25690112);          // 25,690,112
    uint_t* wbits3 = (uint_t*)(ws + 51380224);          // 20,480
    uint_t* wbits1 = (uint_t*)(ws + 51400704);          // 4,096
    uint_t* popcw3 = (uint_t*)(ws + 51404800);          // 8,192
    double* scale3 = (double*)(ws + 51412992);          // 1,024
    double* scale1 = (double*)(ws + 51414016);          // 1,024
    double* sums1  = (double*)(ws + 51415040);          // 2,048
    double* sums2  = (double*)(ws + 51417088);          // 2,048
    uint_t* oflags = (uint_t*)(ws + 51419136);          // 1,024
    uint_t* fin    = (uint_t*)(ws + 51420160);          // 8

    // packed sign planes for conv3 live in d_out (consumed before out_kernel
    // overwrites d_out).
    uint_t* vb1 = (uint_t*)((char*)d_out + 0);          // 8*NPIX*4 = 3,211,264
    float*  outp = (float*)d_out;

    prep_kernel<<<256, 128, 0, stream>>>(w3, w1, wbits3, wbits1, popcw3,
                                         scale3, scale1, sums1, sums2, oflags);
    sign1_kernel<<<dim3(NPIX / 512, 8), 256, 0, stream>>>(x, b1, vb1, oflags, fin);
    conv3_kernel<<<dim3(NPIX / 256, 4), 256, 0, stream>>>(vb1, wbits3, popcw3, y1h, sums1, fin);
    x2c1_kernel<<<dim3(NPIX / 256, 2), 256, 0, stream>>>(x, y1h, sums1, scale3, g1, be1,
                                                         b2_1, a2, b2_2, b3_1,
                                                         wbits1, y3h, sums2, fin);
    out_kernel<<<dim3(NPIX / 2048, 256), 256, 0, stream>>>(x, y1h, y3h,
                                                           sums1, scale3, g1, be1,
                                                           sums2, scale1, g3, be3,
                                                           b2_1, a2, b2_2, b3_1,
                                                           b4_1, a4, b4_2, outp, fin);
}